// Round 3
// baseline (4763.678 us; speedup 1.0000x reference)
//
#include <hip/hip_runtime.h>

typedef unsigned short u16;
typedef unsigned long long u64;
typedef short v8s __attribute__((ext_vector_type(8)));
typedef float v4f __attribute__((ext_vector_type(4)));
typedef unsigned v2u __attribute__((ext_vector_type(2)));
typedef unsigned v4u __attribute__((ext_vector_type(4)));

#define Bb 256
#define Tt 512
#define Dd 64
#define Hh 512
#define G4 2048

#define NGROUP 16    // batch groups (16 batch each)
#define NCHUNK 16    // hidden chunks per group (32 hidden units each)
#define BT 16
#define HC 32
#define NCOL 128     // local gate cols = 4 gates * HC

#define WHH_S 520   // 512 + 8 pad (bf16 elems)
#define WIH_S 72    // 64 + 8 pad
#define SMEM_BYTES (NCOL*WHH_S*2 + NCOL*WIH_S*2)   // 151552 -> 1 block/CU

#define MFMA(a,b,c) __builtin_amdgcn_mfma_f32_16x16x32_bf16((a),(b),(c),0,0,0)

#define SENT 0xFFFFFFFFu   // bf16 -NaN pair; impossible for |h|<1

__device__ __forceinline__ u16 f2bf(float f) {
  unsigned u = __float_as_uint(f);
  unsigned r = (u + 0x7fffu + ((u >> 16) & 1u)) >> 16;
  return (u16)r;
}
__device__ __forceinline__ float bf2f(u16 v) {
  return __uint_as_float(((unsigned)v) << 16);
}
__device__ __forceinline__ float sigm(float x) { return 1.0f / (1.0f + __expf(-x)); }
__device__ __forceinline__ float tanh_f(float x) {
  float a = fabsf(x);
  float e = __expf(-2.0f * a);
  float r = (1.0f - e) / (1.0f + e);
  return copysignf(r, x);
}
__device__ __forceinline__ float softplus_f(float x) { return log1pf(__expf(x)); }

// ---------------------------------------------------------------- prep:
// x fp32 [B][T][D] -> bf16 [T][B][D]; sentinel-fill 4 h ring slots + the
// 256-entry per-block XCD table (handshake array).
__global__ void k_prep(const float* __restrict__ x, u16* __restrict__ x_bf,
                       u16* __restrict__ h_buf)
{
  int stride = gridDim.x * blockDim.x;
  int gid = blockIdx.x * blockDim.x + threadIdx.x;

  // sentinel-fill 4 slots of h ring (1 MB) + xcd table (1 KB): 0xFF bytes
  const int NS = (4 * Bb * Hh * 2 + 256 * 4) / 16;   // uint4 stores
  for (int i = gid; i < NS; i += stride)
    ((uint4*)h_buf)[i] = make_uint4(~0u, ~0u, ~0u, ~0u);

  const int N4 = Tt * Bb * Dd / 4;
  for (int i = gid; i < N4; i += stride) {
    int idx = i * 4;
    int t = idx >> 14;          // / (B*D)
    int rem = idx & 16383;
    int b = rem >> 6;
    int d = rem & 63;
    float4 v = *(const float4*)(x + (size_t)b * (Tt * Dd) + t * Dd + d);
    unsigned lo = (unsigned)f2bf(v.x) | ((unsigned)f2bf(v.y) << 16);
    unsigned hi = (unsigned)f2bf(v.z) | ((unsigned)f2bf(v.w) << 16);
    *(uint2*)(x_bf + idx) = make_uint2(lo, hi);
  }
}

// ---------------------------------------------------------------- main:
// persistent LSTM. 256 blocks x 128 thr (2 waves), static group/chunk.
// GATE-SPLIT waves; ZERO intra-block barriers in the step loop.
//
// R10 kept: DATA-IS-THE-SIGNAL (|h|<1 => bf16 0xFFFF impossible; 4-slot
// sentinel ring; consume in the same poll iteration as discovery).
//
// R11 kept: group-per-XCD mapping + runtime handshake; fast path uses
// intra-XCD L2 for all h traffic.
//
// R12 FIX (R11 hung): sc0 is a SCOPE bit, not an L1-bypass bit -- a
// sc0-only poll load may hit the consumer's own stale L1 sentinel line
// forever. Fast path now does an explicit vector-L1 invalidate
// (`buffer_inv sc0`, the CDNA acquire-fence component) at the top of
// each poll iteration, then PLAIN loads -> L1 miss -> shared-XCD L2 hit
// (~200cy). Producer stores use sc0 (write-through L1 -> L2, short ack;
// this also shrinks the store-drain hidden in each poll vmcnt(0)).
// Insurance against buffer_inv misbehavior: every 8th poll iteration
// issues system-scope (sc0 sc1) loads, which bypass L1 and probe the
// L2 (dirty-hit) -- guarantees forward progress in all cases.
template<bool FAST>
__device__ __forceinline__ void run_steps(
    const u16* const* WhP, const u16* const* WxP,
    const float (*bs)[4], const u16* __restrict__ x_bf,
    u16* __restrict__ h_buf, int bat, int j0, int wv, int q, int ko)
{
  float cc[4] = {0.f, 0.f, 0.f, 0.f};

  for (int t = 0; t < Tt; ++t) {
    v4f ac0 = {0.f,0.f,0.f,0.f}, ac1 = {0.f,0.f,0.f,0.f};
    v4f ac2 = {0.f,0.f,0.f,0.f}, ac3 = {0.f,0.f,0.f,0.f};

    // ---- input projection (h-independent)
    {
      const u16* xb = x_bf + (size_t)t * (Bb * Dd) + bat * Dd + ko;
      #pragma unroll
      for (int ks = 0; ks < 2; ++ks) {
        v8s xf = *(const v8s*)(xb + ks * 32);
        ac0 = MFMA(*(const v8s*)(WxP[0] + ks * 32), xf, ac0);
        ac1 = MFMA(*(const v8s*)(WxP[1] + ks * 32), xf, ac1);
        ac2 = MFMA(*(const v8s*)(WxP[2] + ks * 32), xf, ac2);
        ac3 = MFMA(*(const v8s*)(WxP[3] + ks * 32), xf, ac3);
      }
    }

    if (t > 0) {
      // ---- sentinel-polling recurrent GEMM: same-iteration consume.
      const u16* hb = h_buf + (size_t)(t & 3) * (Bb * Hh) + bat * Hh + ko;
      unsigned done = 0, spin = 0;
      v4u buf[16];
      do {
        if constexpr (FAST) {
          // drop stale L1 lines so plain loads read the shared XCD L2
          asm volatile("buffer_inv sc0" ::: "memory");
        }
        bool sys = !FAST || ((++spin & 7u) == 7u);
        if (sys) {
          #pragma unroll
          for (int c = 0; c < 16; ++c)
            if (!(done & (1u << c)))
              asm volatile("global_load_dwordx4 %0, %1, off offset:%c2 sc0 sc1"
                           : "=v"(buf[c]) : "v"(hb), "i"(c * 64));
        } else {
          #pragma unroll
          for (int c = 0; c < 16; ++c)
            if (!(done & (1u << c)))
              asm volatile("global_load_dwordx4 %0, %1, off offset:%c2"
                           : "=v"(buf[c]) : "v"(hb), "i"(c * 64));
        }
        asm volatile("s_waitcnt vmcnt(0)");
        unsigned ready = 0;
        #pragma unroll
        for (int c = 0; c < 16; ++c)
          if (!(done & (1u << c))) {
            // R9: pin availability after the drain (asm loads invisible
            // to compiler hazard tracking)
            asm volatile("" : "+v"(buf[c]));
            unsigned m0 = buf[c][0] > buf[c][1] ? buf[c][0] : buf[c][1];
            unsigned m1 = buf[c][2] > buf[c][3] ? buf[c][2] : buf[c][3];
            unsigned mx = m0 > m1 ? m0 : m1;
            int ok = (mx != SENT);        // any sentinel dword -> mx==SENT
            if (__all(ok)) ready |= (1u << c);
          }
        #pragma unroll
        for (int c = 0; c < 16; ++c)
          if (ready & (1u << c)) {
            v8s hf = __builtin_bit_cast(v8s, buf[c]);
            ac0 = MFMA(*(const v8s*)(WhP[0] + c * 32), hf, ac0);
            ac1 = MFMA(*(const v8s*)(WhP[1] + c * 32), hf, ac1);
            ac2 = MFMA(*(const v8s*)(WhP[2] + c * 32), hf, ac2);
            ac3 = MFMA(*(const v8s*)(WhP[3] + c * 32), hf, ac3);
          }
        done |= ready;
      } while (done != 0xFFFFu);
    }

    // ---- LSTM update in-register; the 8B h store IS the publication.
    {
      u16 hv[4];
      #pragma unroll
      for (int r = 0; r < 4; ++r) {
        float ig = sigm  (ac0[r] + bs[0][r]);
        float fg = sigm  (ac1[r] + bs[1][r]);
        float gg = tanh_f(ac2[r] + bs[2][r]);
        float og = sigm  (ac3[r] + bs[3][r]);
        cc[r] = fg * cc[r] + ig * gg;
        hv[r] = f2bf(og * tanh_f(cc[r]));
      }
      v2u qv;
      qv[0] = (unsigned)hv[0] | ((unsigned)hv[1] << 16);
      qv[1] = (unsigned)hv[2] | ((unsigned)hv[3] << 16);
      u16* hp = h_buf + (size_t)((t + 1) & 3) * (Bb * Hh) + bat * Hh
              + j0 + wv * 16 + q * 4;
      if constexpr (FAST)
        asm volatile("global_store_dwordx2 %0, %1, off sc0"
                     :: "v"(hp), "v"(qv) : "memory");
      else
        asm volatile("global_store_dwordx2 %0, %1, off sc0 sc1"
                     :: "v"(hp), "v"(qv) : "memory");
    }

    // ---- re-sentinel own produced region of the now-dead slot (t-1)&3.
    // Safe (see R10 note): this step's consume proves all group waves
    // finished reading slot (t-1)&3; clear-vs-rewrite ordering holds
    // transitively through our next poll-loop vmcnt(0) + publish.
    if (t > 0) {
      u16* cp = h_buf + (size_t)((t - 1) & 3) * (Bb * Hh) + bat * Hh
              + j0 + wv * 16 + q * 4;
      v2u sv; sv[0] = SENT; sv[1] = SENT;
      if constexpr (FAST)
        asm volatile("global_store_dwordx2 %0, %1, off sc0"
                     :: "v"(cp), "v"(sv) : "memory");
      else
        asm volatile("global_store_dwordx2 %0, %1, off sc0 sc1"
                     :: "v"(cp), "v"(sv) : "memory");
    }
  }
}

__global__ __launch_bounds__(128, 1) void lstm_main(
    const float* __restrict__ whh_mu, const float* __restrict__ whh_rho, const float* __restrict__ whh_eps,
    const float* __restrict__ wih_mu, const float* __restrict__ wih_rho, const float* __restrict__ wih_eps,
    const float* __restrict__ b_mu,  const float* __restrict__ b_rho,  const float* __restrict__ b_eps,
    const u16* __restrict__ x_bf, u16* __restrict__ h_buf)
{
  extern __shared__ char smem[];
  u16* w_hh_lds = (u16*)smem;                 // [NCOL][WHH_S]
  u16* w_ih_lds = w_hh_lds + NCOL * WHH_S;    // [NCOL][WIH_S]

  const int tid = threadIdx.x;
  // XCD-coherent mapping (assuming round-robin dispatch XCD=blockIdx%8):
  // group g = f(blockIdx&15) -> all 16 blocks of g share blockIdx&15
  // hence one XCD (verified at runtime below); chunk = blockIdx>>4.
  const int jrow  = blockIdx.x & 15;
  const int g     = ((jrow & 7) << 1) | (jrow >> 3);
  const int chunk = blockIdx.x >> 4;
  const int b0    = g * BT;
  const int j0    = chunk * HC;

  unsigned* xcd_arr = (unsigned*)(h_buf + 4 * Bb * Hh);   // 256 entries

  // ---- publish own XCD (system scope) for the group handshake
  unsigned myx;
  asm volatile("s_getreg_b32 %0, hwreg(HW_REG_XCC_ID)" : "=s"(myx));
  myx &= 0xffu;
  unsigned mv = 0x100u | myx;
  if (tid == 0) {
    unsigned* xp = xcd_arr + blockIdx.x;
    asm volatile("global_store_dword %0, %1, off sc0 sc1"
                 :: "v"(xp), "v"(mv) : "memory");
  }

  // ---- sample weight chunk into LDS: one column per thread (128 cols)
  {
    const int lc = tid;                                // 0..127
    const int gcol = (lc >> 5) * Hh + j0 + (lc & 31);  // global gate column
    #pragma unroll 4
    for (int k = 0; k < Hh; ++k) {
      int gi = k * G4 + gcol;
      float w = whh_mu[gi] + softplus_f(whh_rho[gi]) * whh_eps[gi];
      w_hh_lds[lc * WHH_S + k] = f2bf(w);
    }
    #pragma unroll 4
    for (int k = 0; k < Dd; ++k) {
      int gi = k * G4 + gcol;
      float w = wih_mu[gi] + softplus_f(wih_rho[gi]) * wih_eps[gi];
      w_ih_lds[lc * WIH_S + k] = f2bf(w);
    }
  }

  // ---- geometry: wave wv owns hidden-half wv -> tiles rt = gate*2 + wv
  const int lane = tid & 63;
  const int wv   = tid >> 6;
  const int ln   = lane & 15;
  const int q    = lane >> 4;
  const int ko   = q * 8;

  const u16* WhP[4]; const u16* WxP[4];
  #pragma unroll
  for (int gt = 0; gt < 4; ++gt) {
    int rt = gt * 2 + wv;
    WhP[gt] = w_hh_lds + (rt * 16 + ln) * WHH_S + ko;
    WxP[gt] = w_ih_lds + (rt * 16 + ln) * WIH_S + ko;
  }

  const int bat = b0 + ln;   // this lane's batch row (B-operand col)

  // ---- per-lane biases: hidden jj = wv*16 + q*4 + r (4 units, all gates)
  float bs[4][4];
  #pragma unroll
  for (int gt = 0; gt < 4; ++gt)
    #pragma unroll
    for (int r = 0; r < 4; ++r) {
      int colg = gt * Hh + j0 + wv * 16 + q * 4 + r;
      bs[gt][r] = b_mu[colg] + softplus_f(b_rho[colg]) * b_eps[colg];
    }

  // ---- group XCD-uniformity handshake (one-time, system scope).
  // Lane ln polls member block c=ln of this group (blockIdx = ln*16+jrow);
  // lanes 16-63 duplicate lanes 0-15 (harmless).
  int fast;
  {
    const unsigned* xp = xcd_arr + (lane & 15) * 16 + jrow;
    for (;;) {
      unsigned v;
      asm volatile("global_load_dword %0, %1, off sc0 sc1"
                   : "=v"(v) : "v"(xp));
      asm volatile("s_waitcnt vmcnt(0)");
      asm volatile("" : "+v"(v));
      if (__all((int)(v != SENT))) {
        fast = __all((int)(v == mv));
        break;
      }
    }
  }

  __syncthreads();   // weights-in-LDS ready (one-time; only barrier used)

  if (fast)
    run_steps<true >(WhP, WxP, bs, x_bf, h_buf, bat, j0, wv, q, ko);
  else
    run_steps<false>(WhP, WxP, bs, x_bf, h_buf, bat, j0, wv, q, ko);
}

// ---------------------------------------------------------------- epilogue:
// out[b] = h_last[b,:] . lin_w + lin_b
// h(T) was published at t=511 into slot (511+1)&3 = 0 -> h_buf base.
// Dispatch-boundary release writes back the per-XCD L2s, so fast-path h
// (dirty L2 lines) is visible here.
__global__ void k_out(const u16* __restrict__ h, const float* __restrict__ lw,
                      const float* __restrict__ lb, float* __restrict__ out)
{
  int b = blockIdx.x * 64 + threadIdx.x;
  if (b >= Bb) return;
  const u16* hr = h + b * Hh;
  float acc = 0.f;
  #pragma unroll 8
  for (int k = 0; k < Hh; ++k) acc += bf2f(hr[k]) * lw[k];
  out[b] = acc + lb[0];
}

extern "C" void kernel_launch(void* const* d_in, const int* in_sizes, int n_in,
                              void* d_out, int out_size, void* d_ws, size_t ws_size,
                              hipStream_t stream)
{
  (void)in_sizes; (void)n_in; (void)out_size; (void)ws_size;
  const float* x       = (const float*)d_in[0];
  const float* wih_mu  = (const float*)d_in[1];
  const float* wih_rho = (const float*)d_in[2];
  const float* wih_eps = (const float*)d_in[3];
  const float* whh_mu  = (const float*)d_in[4];
  const float* whh_rho = (const float*)d_in[5];
  const float* whh_eps = (const float*)d_in[6];
  const float* b_mu    = (const float*)d_in[7];
  const float* b_rho   = (const float*)d_in[8];
  const float* b_eps   = (const float*)d_in[9];
  const float* lin_w   = (const float*)d_in[10];
  const float* lin_b   = (const float*)d_in[11];
  float* out = (float*)d_out;

  // workspace layout
  u16* x_bf  = (u16*)d_ws;                       // T*B*D bf16  = 16 MB
  u16* h_buf = x_bf + (size_t)Tt * Bb * Dd;      // 4 ring slots * B*H bf16 = 1 MB
                                                 // + 256 u32 xcd table

  k_prep<<<2048, 256, 0, stream>>>(x, x_bf, h_buf);

  hipFuncSetAttribute(reinterpret_cast<const void*>(lstm_main),
                      hipFuncAttributeMaxDynamicSharedMemorySize, SMEM_BYTES);
  lstm_main<<<NGROUP * NCHUNK, 128, SMEM_BYTES, stream>>>(
      whh_mu, whh_rho, whh_eps, wih_mu, wih_rho, wih_eps,
      b_mu, b_rho, b_eps, x_bf, h_buf);

  k_out<<<(Bb + 63) / 64, 64, 0, stream>>>(h_buf, lin_w, lin_b, out);
}

// Round 5
// 2530.615 us; speedup vs baseline: 1.8824x; 1.8824x over previous
//
#include <hip/hip_runtime.h>

typedef unsigned short u16;
typedef unsigned long long u64;
typedef short v8s __attribute__((ext_vector_type(8)));
typedef float v4f __attribute__((ext_vector_type(4)));
typedef unsigned v2u __attribute__((ext_vector_type(2)));
typedef unsigned v4u __attribute__((ext_vector_type(4)));

#define Bb 256
#define Tt 512
#define Dd 64
#define Hh 512
#define G4 2048

#define NGROUP 16    // batch groups (16 batch each)
#define NCHUNK 16    // hidden chunks per group (32 hidden units each)
#define BT 16
#define HC 32
#define NCOL 128     // local gate cols = 4 gates * HC

#define WHH_S 520   // 512 + 8 pad (bf16 elems)
#define WIH_S 72    // 64 + 8 pad
#define SMEM_BYTES (NCOL*WHH_S*2 + NCOL*WIH_S*2)   // 151552 -> 1 block/CU

#define MFMA(a,b,c) __builtin_amdgcn_mfma_f32_16x16x32_bf16((a),(b),(c),0,0,0)

#define SENT 0xFFFFFFFFu   // bf16 -NaN pair; impossible for |h|<1

__device__ __forceinline__ u16 f2bf(float f) {
  unsigned u = __float_as_uint(f);
  unsigned r = (u + 0x7fffu + ((u >> 16) & 1u)) >> 16;
  return (u16)r;
}
__device__ __forceinline__ float bf2f(u16 v) {
  return __uint_as_float(((unsigned)v) << 16);
}
__device__ __forceinline__ float sigm(float x) { return 1.0f / (1.0f + __expf(-x)); }
__device__ __forceinline__ float tanh_f(float x) {
  float a = fabsf(x);
  float e = __expf(-2.0f * a);
  float r = (1.0f - e) / (1.0f + e);
  return copysignf(r, x);
}
__device__ __forceinline__ float softplus_f(float x) { return log1pf(__expf(x)); }

// ---------------------------------------------------------------- prep:
// x fp32 [B][T][D] -> bf16 [T][B][D]; sentinel-fill 4 h ring slots + xcd
// handshake table; ZERO the per-group barrier counters.
__global__ void k_prep(const float* __restrict__ x, u16* __restrict__ x_bf,
                       u16* __restrict__ h_buf)
{
  int stride = gridDim.x * blockDim.x;
  int gid = blockIdx.x * blockDim.x + threadIdx.x;

  // sentinel-fill 4 slots of h ring (1 MB) + xcd table (1 KB)
  const int NS = (4 * Bb * Hh * 2 + 256 * 4) / 16;   // uint4 stores
  for (int i = gid; i < NS; i += stride)
    ((uint4*)h_buf)[i] = make_uint4(~0u, ~0u, ~0u, ~0u);

  // zero barrier counters: 16 groups x 4 slots x 32 u32 (128B stride) = 8KB
  uint4* cnt4 = (uint4*)((unsigned*)(h_buf + 4 * Bb * Hh) + 256);
  for (int i = gid; i < 512; i += stride)
    cnt4[i] = make_uint4(0u, 0u, 0u, 0u);

  const int N4 = Tt * Bb * Dd / 4;
  for (int i = gid; i < N4; i += stride) {
    int idx = i * 4;
    int t = idx >> 14;          // / (B*D)
    int rem = idx & 16383;
    int b = rem >> 6;
    int d = rem & 63;
    float4 v = *(const float4*)(x + (size_t)b * (Tt * Dd) + t * Dd + d);
    unsigned lo = (unsigned)f2bf(v.x) | ((unsigned)f2bf(v.y) << 16);
    unsigned hi = (unsigned)f2bf(v.z) | ((unsigned)f2bf(v.w) << 16);
    *(uint2*)(x_bf + idx) = make_uint2(lo, hi);
  }
}

// ---------------------------------------------------------------- main:
// persistent LSTM. 256 blocks x 128 thr (2 waves), static group/chunk.
// GATE-SPLIT waves; ZERO intra-block barriers in the step loop.
//
// R13 failed correctness (stale h at depth 2): on gfx940+ sc0/sc1 are a
// 2-bit SCOPE field (00=CU,01=SE,10=dev,11=sys). An sc0 (SE-scope) store's
// vmcnt ack does NOT imply TCC commit, so the counter atomic (executed AT
// the TCC) could land before the h data -> barrier passed on stale L2.
//
// R14 fixes the release + adds an airtight net:
//  - PUBLISH h VIA global_atomic_swap_x2 (plain scope, no return): atomics
//    always execute at the TCC, so their vmcnt ack IS L2 commit. Then
//    vmcnt(0) -> counter atomic_add. Release chain fully L2-committed.
//  - Depth-4 SENTINEL ring restored as verification: per 8B region the
//    same wave writes h(t-4) -> SENT (clear @ t-3) -> h(t); same-address
//    same-wave stores commit to L2 in order, so a post-inv load returns
//    SENT (cheap retry) or h(t), NEVER h(t-4). Even a broken barrier
//    degrades to retries, not corruption.
//  - Barrier gates entry -> typical 1 buffer_inv + 1 bulk load per step
//    (R12's inv-per-iteration cascade structurally cannot recur).
//  - Slow path (handshake fail): R10's device-scope sentinel protocol,
//    verbatim (benched 2.5ms).
template<bool FAST>
__device__ __forceinline__ void run_steps(
    const u16* const* WhP, const u16* const* WxP,
    const float (*bs)[4], const u16* __restrict__ x_bf,
    u16* __restrict__ h_buf, unsigned* __restrict__ cnt_base,
    int g, int lane, int bat, int j0, int wv, int q, int ko)
{
  float cc[4] = {0.f, 0.f, 0.f, 0.f};

  for (int t = 0; t < Tt; ++t) {
    v4f ac0 = {0.f,0.f,0.f,0.f}, ac1 = {0.f,0.f,0.f,0.f};
    v4f ac2 = {0.f,0.f,0.f,0.f}, ac3 = {0.f,0.f,0.f,0.f};

    // ---- input projection (h-independent; overlaps barrier wait skew)
    {
      const u16* xb = x_bf + (size_t)t * (Bb * Dd) + bat * Dd + ko;
      #pragma unroll
      for (int ks = 0; ks < 2; ++ks) {
        v8s xf = *(const v8s*)(xb + ks * 32);
        ac0 = MFMA(*(const v8s*)(WxP[0] + ks * 32), xf, ac0);
        ac1 = MFMA(*(const v8s*)(WxP[1] + ks * 32), xf, ac1);
        ac2 = MFMA(*(const v8s*)(WxP[2] + ks * 32), xf, ac2);
        ac3 = MFMA(*(const v8s*)(WxP[3] + ks * 32), xf, ac3);
      }
    }

    if (t > 0) {
      const u16* hb = h_buf + (size_t)(t & 3) * (Bb * Hh) + bat * Hh + ko;
      if constexpr (FAST) {
        // ---- L2 atomic barrier: wait until all 32 group waves published
        // h(t) into slot t&3. target = 32 * (#publishes into this slot).
        unsigned* cq = cnt_base + (g * 4 + (t & 3)) * 32;
        const unsigned target = 32u * ((unsigned)(t + 3) >> 2);
        unsigned zero = 0;
        for (;;) {
          unsigned rv = 0;
          if (lane == 0)
            asm volatile("global_atomic_or %0, %1, %2, off sc0"
                         : "=v"(rv) : "v"(cq), "v"(zero) : "memory");
          asm volatile("s_waitcnt vmcnt(0)");
          asm volatile("" : "+v"(rv));
          if (__builtin_amdgcn_readfirstlane(rv) >= target) break;
        }
        // ---- acquire + verified consume (typically ONE iteration)
        unsigned done = 0;
        v4u buf[16];
        do {
          // drop stale L1 lines so plain loads read the shared XCD L2
          asm volatile("buffer_inv sc0" ::: "memory");
          #pragma unroll
          for (int c = 0; c < 16; ++c)
            if (!(done & (1u << c)))
              asm volatile("global_load_dwordx4 %0, %1, off offset:%c2"
                           : "=v"(buf[c]) : "v"(hb), "i"(c * 64));
          asm volatile("s_waitcnt vmcnt(0)");
          unsigned ready = 0;
          #pragma unroll
          for (int c = 0; c < 16; ++c)
            if (!(done & (1u << c))) {
              asm volatile("" : "+v"(buf[c]));   // R9: pin after drain
              unsigned m0 = buf[c][0] > buf[c][1] ? buf[c][0] : buf[c][1];
              unsigned m1 = buf[c][2] > buf[c][3] ? buf[c][2] : buf[c][3];
              unsigned mx = m0 > m1 ? m0 : m1;
              int ok = (mx != SENT);
              if (__all(ok)) ready |= (1u << c);
            }
          #pragma unroll
          for (int c = 0; c < 16; ++c)
            if (ready & (1u << c)) {
              v8s hf = __builtin_bit_cast(v8s, buf[c]);
              ac0 = MFMA(*(const v8s*)(WhP[0] + c * 32), hf, ac0);
              ac1 = MFMA(*(const v8s*)(WhP[1] + c * 32), hf, ac1);
              ac2 = MFMA(*(const v8s*)(WhP[2] + c * 32), hf, ac2);
              ac3 = MFMA(*(const v8s*)(WhP[3] + c * 32), hf, ac3);
            }
          done |= ready;
        } while (done != 0xFFFFu);
      } else {
        // ---- R10 device-scope sentinel protocol (verbatim slow path)
        unsigned done = 0;
        v4u buf[16];
        do {
          #pragma unroll
          for (int c = 0; c < 16; ++c)
            if (!(done & (1u << c)))
              asm volatile("global_load_dwordx4 %0, %1, off offset:%c2 sc0 sc1"
                           : "=v"(buf[c]) : "v"(hb), "i"(c * 64));
          asm volatile("s_waitcnt vmcnt(0)");
          unsigned ready = 0;
          #pragma unroll
          for (int c = 0; c < 16; ++c)
            if (!(done & (1u << c))) {
              asm volatile("" : "+v"(buf[c]));
              unsigned m0 = buf[c][0] > buf[c][1] ? buf[c][0] : buf[c][1];
              unsigned m1 = buf[c][2] > buf[c][3] ? buf[c][2] : buf[c][3];
              unsigned mx = m0 > m1 ? m0 : m1;
              int ok = (mx != SENT);
              if (__all(ok)) ready |= (1u << c);
            }
          #pragma unroll
          for (int c = 0; c < 16; ++c)
            if (ready & (1u << c)) {
              v8s hf = __builtin_bit_cast(v8s, buf[c]);
              ac0 = MFMA(*(const v8s*)(WhP[0] + c * 32), hf, ac0);
              ac1 = MFMA(*(const v8s*)(WhP[1] + c * 32), hf, ac1);
              ac2 = MFMA(*(const v8s*)(WhP[2] + c * 32), hf, ac2);
              ac3 = MFMA(*(const v8s*)(WhP[3] + c * 32), hf, ac3);
            }
          done |= ready;
        } while (done != 0xFFFFu);
      }
    }

    // ---- LSTM update fully in-register; 8B h publication
    {
      u16 hv[4];
      #pragma unroll
      for (int r = 0; r < 4; ++r) {
        float ig = sigm  (ac0[r] + bs[0][r]);
        float fg = sigm  (ac1[r] + bs[1][r]);
        float gg = tanh_f(ac2[r] + bs[2][r]);
        float og = sigm  (ac3[r] + bs[3][r]);
        cc[r] = fg * cc[r] + ig * gg;
        hv[r] = f2bf(og * tanh_f(cc[r]));
      }
      v2u qv;
      qv[0] = (unsigned)hv[0] | ((unsigned)hv[1] << 16);
      qv[1] = (unsigned)hv[2] | ((unsigned)hv[3] << 16);
      u16* hp = h_buf + (size_t)((t + 1) & 3) * (Bb * Hh) + bat * Hh
              + j0 + wv * 16 + q * 4;
      if constexpr (FAST) {
        // atomic swap = executes AT the TCC -> vmcnt ack IS L2 commit
        asm volatile("global_atomic_swap_x2 %0, %1, off"
                     :: "v"(hp), "v"(qv) : "memory");
        asm volatile("s_waitcnt vmcnt(0)" ::: "memory");
        if (lane == 0) {
          unsigned* pq = cnt_base + (g * 4 + ((t + 1) & 3)) * 32;
          unsigned one = 1;
          asm volatile("global_atomic_add %0, %1, off"
                       :: "v"(pq), "v"(one) : "memory");
        }
      } else {
        asm volatile("global_store_dwordx2 %0, %1, off sc0 sc1"
                     :: "v"(hp), "v"(qv) : "memory");
      }
    }

    // ---- re-sentinel own produced region of the now-dead slot (t-1)&3.
    // Safe: this step's consume (or barrier) proves all group waves
    // finished reading slot (t-1)&3. Same-wave same-address ordering
    // guarantees L2 sees clear-then-next-h in order.
    if (t > 0) {
      u16* cp = h_buf + (size_t)((t - 1) & 3) * (Bb * Hh) + bat * Hh
              + j0 + wv * 16 + q * 4;
      v2u sv; sv[0] = SENT; sv[1] = SENT;
      if constexpr (FAST)
        asm volatile("global_store_dwordx2 %0, %1, off"
                     :: "v"(cp), "v"(sv) : "memory");
      else
        asm volatile("global_store_dwordx2 %0, %1, off sc0 sc1"
                     :: "v"(cp), "v"(sv) : "memory");
    }
  }
}

__global__ __launch_bounds__(128, 1) void lstm_main(
    const float* __restrict__ whh_mu, const float* __restrict__ whh_rho, const float* __restrict__ whh_eps,
    const float* __restrict__ wih_mu, const float* __restrict__ wih_rho, const float* __restrict__ wih_eps,
    const float* __restrict__ b_mu,  const float* __restrict__ b_rho,  const float* __restrict__ b_eps,
    const u16* __restrict__ x_bf, u16* __restrict__ h_buf)
{
  extern __shared__ char smem[];
  u16* w_hh_lds = (u16*)smem;                 // [NCOL][WHH_S]
  u16* w_ih_lds = w_hh_lds + NCOL * WHH_S;    // [NCOL][WIH_S]

  const int tid = threadIdx.x;
  // XCD-coherent mapping (round-robin dispatch XCD=blockIdx%8, verified
  // at runtime): all 16 blocks of group g share blockIdx&15 -> one XCD.
  const int jrow  = blockIdx.x & 15;
  const int g     = ((jrow & 7) << 1) | (jrow >> 3);
  const int chunk = blockIdx.x >> 4;
  const int b0    = g * BT;
  const int j0    = chunk * HC;

  unsigned* xcd_arr  = (unsigned*)(h_buf + 4 * Bb * Hh);   // 256 entries
  unsigned* cnt_base = xcd_arr + 256;                      // 16g x 4 x 32 u32

  // ---- publish own XCD (system scope) for the group handshake
  unsigned myx;
  asm volatile("s_getreg_b32 %0, hwreg(HW_REG_XCC_ID)" : "=s"(myx));
  myx &= 0xffu;
  unsigned mv = 0x100u | myx;
  if (tid == 0) {
    unsigned* xp = xcd_arr + blockIdx.x;
    asm volatile("global_store_dword %0, %1, off sc0 sc1"
                 :: "v"(xp), "v"(mv) : "memory");
  }

  // ---- sample weight chunk into LDS: one column per thread (128 cols)
  {
    const int lc = tid;                                // 0..127
    const int gcol = (lc >> 5) * Hh + j0 + (lc & 31);  // global gate column
    #pragma unroll 4
    for (int k = 0; k < Hh; ++k) {
      int gi = k * G4 + gcol;
      float w = whh_mu[gi] + softplus_f(whh_rho[gi]) * whh_eps[gi];
      w_hh_lds[lc * WHH_S + k] = f2bf(w);
    }
    #pragma unroll 4
    for (int k = 0; k < Dd; ++k) {
      int gi = k * G4 + gcol;
      float w = wih_mu[gi] + softplus_f(wih_rho[gi]) * wih_eps[gi];
      w_ih_lds[lc * WIH_S + k] = f2bf(w);
    }
  }

  // ---- geometry: wave wv owns hidden-half wv -> tiles rt = gate*2 + wv
  const int lane = tid & 63;
  const int wv   = tid >> 6;
  const int ln   = lane & 15;
  const int q    = lane >> 4;
  const int ko   = q * 8;

  const u16* WhP[4]; const u16* WxP[4];
  #pragma unroll
  for (int gt = 0; gt < 4; ++gt) {
    int rt = gt * 2 + wv;
    WhP[gt] = w_hh_lds + (rt * 16 + ln) * WHH_S + ko;
    WxP[gt] = w_ih_lds + (rt * 16 + ln) * WIH_S + ko;
  }

  const int bat = b0 + ln;   // this lane's batch row (B-operand col)

  // ---- per-lane biases: hidden jj = wv*16 + q*4 + r (4 units, all gates)
  float bs[4][4];
  #pragma unroll
  for (int gt = 0; gt < 4; ++gt)
    #pragma unroll
    for (int r = 0; r < 4; ++r) {
      int colg = gt * Hh + j0 + wv * 16 + q * 4 + r;
      bs[gt][r] = b_mu[colg] + softplus_f(b_rho[colg]) * b_eps[colg];
    }

  // ---- group XCD-uniformity handshake (one-time, system scope).
  int fast;
  {
    const unsigned* xp = xcd_arr + (lane & 15) * 16 + jrow;
    for (;;) {
      unsigned v;
      asm volatile("global_load_dword %0, %1, off sc0 sc1"
                   : "=v"(v) : "v"(xp));
      asm volatile("s_waitcnt vmcnt(0)");
      asm volatile("" : "+v"(v));
      if (__all((int)(v != SENT))) {
        fast = __all((int)(v == mv));
        break;
      }
    }
  }

  __syncthreads();   // weights-in-LDS ready (one-time; only barrier used)

  if (fast)
    run_steps<true >(WhP, WxP, bs, x_bf, h_buf, cnt_base, g, lane,
                     bat, j0, wv, q, ko);
  else
    run_steps<false>(WhP, WxP, bs, x_bf, h_buf, cnt_base, g, lane,
                     bat, j0, wv, q, ko);
}

// ---------------------------------------------------------------- epilogue:
// out[b] = h_last[b,:] . lin_w + lin_b
// h(512) lives in slot (511+1)&3 = 0 -> h_buf base (both paths).
// Dispatch-boundary release writes back the per-XCD L2s (R12-verified).
__global__ void k_out(const u16* __restrict__ h, const float* __restrict__ lw,
                      const float* __restrict__ lb, float* __restrict__ out)
{
  int b = blockIdx.x * 64 + threadIdx.x;
  if (b >= Bb) return;
  const u16* hr = h + b * Hh;
  float acc = 0.f;
  #pragma unroll 8
  for (int k = 0; k < Hh; ++k) acc += bf2f(hr[k]) * lw[k];
  out[b] = acc + lb[0];
}

extern "C" void kernel_launch(void* const* d_in, const int* in_sizes, int n_in,
                              void* d_out, int out_size, void* d_ws, size_t ws_size,
                              hipStream_t stream)
{
  (void)in_sizes; (void)n_in; (void)out_size; (void)ws_size;
  const float* x       = (const float*)d_in[0];
  const float* wih_mu  = (const float*)d_in[1];
  const float* wih_rho = (const float*)d_in[2];
  const float* wih_eps = (const float*)d_in[3];
  const float* whh_mu  = (const float*)d_in[4];
  const float* whh_rho = (const float*)d_in[5];
  const float* whh_eps = (const float*)d_in[6];
  const float* b_mu    = (const float*)d_in[7];
  const float* b_rho   = (const float*)d_in[8];
  const float* b_eps   = (const float*)d_in[9];
  const float* lin_w   = (const float*)d_in[10];
  const float* lin_b   = (const float*)d_in[11];
  float* out = (float*)d_out;

  // workspace layout
  u16* x_bf  = (u16*)d_ws;                       // T*B*D bf16  = 16 MB
  u16* h_buf = x_bf + (size_t)Tt * Bb * Dd;      // 4 ring slots (1 MB)
                                                 // + 256 u32 xcd table
                                                 // + 8 KB barrier counters

  k_prep<<<2048, 256, 0, stream>>>(x, x_bf, h_buf);

  hipFuncSetAttribute(reinterpret_cast<const void*>(lstm_main),
                      hipFuncAttributeMaxDynamicSharedMemorySize, SMEM_BYTES);
  lstm_main<<<NGROUP * NCHUNK, 128, SMEM_BYTES, stream>>>(
      whh_mu, whh_rho, whh_eps, wih_mu, wih_rho, wih_eps,
      b_mu, b_rho, b_eps, x_bf, h_buf);

  k_out<<<(Bb + 63) / 64, 64, 0, stream>>>(h_buf, lin_w, lin_b, out);
}

// Round 7
// 2064.359 us; speedup vs baseline: 2.3076x; 1.2259x over previous
//
#include <hip/hip_runtime.h>

typedef unsigned short u16;
typedef unsigned long long u64;
typedef short v8s __attribute__((ext_vector_type(8)));
typedef float v4f __attribute__((ext_vector_type(4)));
typedef unsigned v2u __attribute__((ext_vector_type(2)));
typedef unsigned v4u __attribute__((ext_vector_type(4)));

#define Bb 256
#define Tt 512
#define Dd 64
#define Hh 512
#define G4 2048

#define NGROUP 16    // batch groups (16 batch each)
#define NCHUNK 16    // hidden chunks per group (32 hidden units each)
#define BT 16
#define HC 32
#define NCOL 128     // local gate cols = 4 gates * HC

#define WHH_S 520   // 512 + 8 pad (bf16 elems)
#define WIH_S 72    // 64 + 8 pad
#define SMEM_BYTES (NCOL*WHH_S*2 + NCOL*WIH_S*2)   // 151552 -> 1 block/CU

#define MFMA(a,b,c) __builtin_amdgcn_mfma_f32_16x16x32_bf16((a),(b),(c),0,0,0)

#define SENT 0xFFFFFFFFu   // bf16 -NaN pair; impossible for |h|<1

__device__ __forceinline__ u16 f2bf(float f) {
  unsigned u = __float_as_uint(f);
  unsigned r = (u + 0x7fffu + ((u >> 16) & 1u)) >> 16;
  return (u16)r;
}
__device__ __forceinline__ float bf2f(u16 v) {
  return __uint_as_float(((unsigned)v) << 16);
}
__device__ __forceinline__ float sigm(float x) { return 1.0f / (1.0f + __expf(-x)); }
__device__ __forceinline__ float tanh_f(float x) {
  float a = fabsf(x);
  float e = __expf(-2.0f * a);
  float r = (1.0f - e) / (1.0f + e);
  return copysignf(r, x);
}
__device__ __forceinline__ float softplus_f(float x) { return log1pf(__expf(x)); }

// ---------------------------------------------------------------- prep:
// x fp32 [B][T][D] -> bf16 [T][B][D]; sentinel-fill 4 h ring slots + xcd
// handshake table.
__global__ void k_prep(const float* __restrict__ x, u16* __restrict__ x_bf,
                       u16* __restrict__ h_buf)
{
  int stride = gridDim.x * blockDim.x;
  int gid = blockIdx.x * blockDim.x + threadIdx.x;

  // sentinel-fill 4 slots of h ring (1 MB) + xcd table (1 KB)
  const int NS = (4 * Bb * Hh * 2 + 256 * 4) / 16;   // uint4 stores
  for (int i = gid; i < NS; i += stride)
    ((uint4*)h_buf)[i] = make_uint4(~0u, ~0u, ~0u, ~0u);

  const int N4 = Tt * Bb * Dd / 4;
  for (int i = gid; i < N4; i += stride) {
    int idx = i * 4;
    int t = idx >> 14;          // / (B*D)
    int rem = idx & 16383;
    int b = rem >> 6;
    int d = rem & 63;
    float4 v = *(const float4*)(x + (size_t)b * (Tt * Dd) + t * Dd + d);
    unsigned lo = (unsigned)f2bf(v.x) | ((unsigned)f2bf(v.y) << 16);
    unsigned hi = (unsigned)f2bf(v.z) | ((unsigned)f2bf(v.w) << 16);
    *(uint2*)(x_bf + idx) = make_uint2(lo, hi);
  }
}

// ---------------------------------------------------------------- main:
// persistent LSTM. 256 blocks x 128 thr (2 waves), static group/chunk.
// GATE-SPLIT waves; ZERO intra-block barriers in the step loop.
//
// HW facts from PASSING runs only:
//  (a) sc0 (SE-scope) stores commit into the shared XCD L2 and STAY there
//      (R12: WRITE_SIZE 262MB->1MB) and are readable by other CUs via
//      sc0 sc1 loads (R12 correctness rode on exactly this pairing).
//  (b) sc0 sc1 loads always observe committed data (R10/R14 correct).
//  (c) depth-4 sentinel ring turns store-commit skew into cheap retries,
//      never corruption (R10/R12/R14 all passed on it).
//  (d) global atomics execute at the die-level coherence point -> ~900cy
//      legs; useless for intra-XCD sync (R14: flat + 280MB writes).
//  (e) buffer_inv + PLAIN load does NOT deliver fresh data reliably
//      (R15 hang; R12's correctness came from its every-8th sc0sc1
//      insurance loads). PLAIN stores likewise suspect. Banned.
//
// R16 = R10's event-driven sentinel protocol VERBATIM, with producer
// stores downgraded sc0sc1 -> sc0 in XCD-verified groups. Loads stay
// sc0 sc1. Discovery legs shrink from store-to-L3 + L3-load (~1.8k cy)
// to store-to-L2 + L2-dirty-hit (~600-700 cy). Slow path (handshake
// fail) = identical code with system-scope stores (benched 2.5ms).
template<bool FAST>
__device__ __forceinline__ void run_steps(
    const u16* const* WhP, const u16* const* WxP,
    const float (*bs)[4], const u16* __restrict__ x_bf,
    u16* __restrict__ h_buf, int bat, int j0, int wv, int q, int ko)
{
  float cc[4] = {0.f, 0.f, 0.f, 0.f};

  for (int t = 0; t < Tt; ++t) {
    v4f ac0 = {0.f,0.f,0.f,0.f}, ac1 = {0.f,0.f,0.f,0.f};
    v4f ac2 = {0.f,0.f,0.f,0.f}, ac3 = {0.f,0.f,0.f,0.f};

    // ---- input projection (h-independent; overlaps first poll RTT)
    {
      const u16* xb = x_bf + (size_t)t * (Bb * Dd) + bat * Dd + ko;
      #pragma unroll
      for (int ks = 0; ks < 2; ++ks) {
        v8s xf = *(const v8s*)(xb + ks * 32);
        ac0 = MFMA(*(const v8s*)(WxP[0] + ks * 32), xf, ac0);
        ac1 = MFMA(*(const v8s*)(WxP[1] + ks * 32), xf, ac1);
        ac2 = MFMA(*(const v8s*)(WxP[2] + ks * 32), xf, ac2);
        ac3 = MFMA(*(const v8s*)(WxP[3] + ks * 32), xf, ac3);
      }
    }

    if (t > 0) {
      // ---- event-driven sentinel consume: the data load IS the poll;
      // each ready chunk is MFMA'd the iteration its bytes land.
      const u16* hb = h_buf + (size_t)(t & 3) * (Bb * Hh) + bat * Hh + ko;
      unsigned done = 0;
      v4u buf[16];
      do {
        #pragma unroll
        for (int c = 0; c < 16; ++c)
          if (!(done & (1u << c)))
            asm volatile("global_load_dwordx4 %0, %1, off offset:%c2 sc0 sc1"
                         : "=v"(buf[c]) : "v"(hb), "i"(c * 64));
        asm volatile("s_waitcnt vmcnt(0)");
        unsigned ready = 0;
        #pragma unroll
        for (int c = 0; c < 16; ++c)
          if (!(done & (1u << c))) {
            asm volatile("" : "+v"(buf[c]));   // R9: pin after drain
            unsigned m0 = buf[c][0] > buf[c][1] ? buf[c][0] : buf[c][1];
            unsigned m1 = buf[c][2] > buf[c][3] ? buf[c][2] : buf[c][3];
            unsigned mx = m0 > m1 ? m0 : m1;
            int ok = (mx != SENT);             // any sentinel dword -> SENT
            if (__all(ok)) ready |= (1u << c);
          }
        #pragma unroll
        for (int c = 0; c < 16; ++c)
          if (ready & (1u << c)) {
            v8s hf = __builtin_bit_cast(v8s, buf[c]);
            ac0 = MFMA(*(const v8s*)(WhP[0] + c * 32), hf, ac0);
            ac1 = MFMA(*(const v8s*)(WhP[1] + c * 32), hf, ac1);
            ac2 = MFMA(*(const v8s*)(WhP[2] + c * 32), hf, ac2);
            ac3 = MFMA(*(const v8s*)(WhP[3] + c * 32), hf, ac3);
          }
        done |= ready;
      } while (done != 0xFFFFu);
    }

    // ---- LSTM update fully in-register; the 8B h store IS the
    // publication. FAST: sc0 -> commits into shared XCD L2 (fact a).
    {
      u16 hv[4];
      #pragma unroll
      for (int r = 0; r < 4; ++r) {
        float ig = sigm  (ac0[r] + bs[0][r]);
        float fg = sigm  (ac1[r] + bs[1][r]);
        float gg = tanh_f(ac2[r] + bs[2][r]);
        float og = sigm  (ac3[r] + bs[3][r]);
        cc[r] = fg * cc[r] + ig * gg;
        hv[r] = f2bf(og * tanh_f(cc[r]));
      }
      v2u qv;
      qv[0] = (unsigned)hv[0] | ((unsigned)hv[1] << 16);
      qv[1] = (unsigned)hv[2] | ((unsigned)hv[3] << 16);
      u16* hp = h_buf + (size_t)((t + 1) & 3) * (Bb * Hh) + bat * Hh
              + j0 + wv * 16 + q * 4;
      if constexpr (FAST)
        asm volatile("global_store_dwordx2 %0, %1, off sc0"
                     :: "v"(hp), "v"(qv) : "memory");
      else
        asm volatile("global_store_dwordx2 %0, %1, off sc0 sc1"
                     :: "v"(hp), "v"(qv) : "memory");
    }

    // ---- re-sentinel own produced region of the now-dead slot (t-1)&3.
    // Safe: this step's consume proves all group waves finished reading
    // slot (t-1)&3; per-address same-wave store order (clear @ t, next h
    // @ t+2) guarantees L2 sees clear-then-h in order; an early-visible
    // clear is just a retry at the consumer (fact c).
    if (t > 0) {
      u16* cp = h_buf + (size_t)((t - 1) & 3) * (Bb * Hh) + bat * Hh
              + j0 + wv * 16 + q * 4;
      v2u sv; sv[0] = SENT; sv[1] = SENT;
      if constexpr (FAST)
        asm volatile("global_store_dwordx2 %0, %1, off sc0"
                     :: "v"(cp), "v"(sv) : "memory");
      else
        asm volatile("global_store_dwordx2 %0, %1, off sc0 sc1"
                     :: "v"(cp), "v"(sv) : "memory");
    }
  }
}

__global__ __launch_bounds__(128, 1) void lstm_main(
    const float* __restrict__ whh_mu, const float* __restrict__ whh_rho, const float* __restrict__ whh_eps,
    const float* __restrict__ wih_mu, const float* __restrict__ wih_rho, const float* __restrict__ wih_eps,
    const float* __restrict__ b_mu,  const float* __restrict__ b_rho,  const float* __restrict__ b_eps,
    const u16* __restrict__ x_bf, u16* __restrict__ h_buf)
{
  extern __shared__ char smem[];
  u16* w_hh_lds = (u16*)smem;                 // [NCOL][WHH_S]
  u16* w_ih_lds = w_hh_lds + NCOL * WHH_S;    // [NCOL][WIH_S]

  const int tid = threadIdx.x;
  // XCD-coherent mapping (round-robin dispatch XCD=blockIdx%8, verified
  // at runtime): all 16 blocks of group g share blockIdx&15 -> one XCD.
  const int jrow  = blockIdx.x & 15;
  const int g     = ((jrow & 7) << 1) | (jrow >> 3);
  const int chunk = blockIdx.x >> 4;
  const int b0    = g * BT;
  const int j0    = chunk * HC;

  unsigned* xcd_arr = (unsigned*)(h_buf + 4 * Bb * Hh);   // 256 entries

  // ---- publish own XCD (system scope) for the group handshake
  unsigned myx;
  asm volatile("s_getreg_b32 %0, hwreg(HW_REG_XCC_ID)" : "=s"(myx));
  myx &= 0xffu;
  unsigned mv = 0x100u | myx;
  if (tid == 0) {
    unsigned* xp = xcd_arr + blockIdx.x;
    asm volatile("global_store_dword %0, %1, off sc0 sc1"
                 :: "v"(xp), "v"(mv) : "memory");
  }

  // ---- sample weight chunk into LDS: one column per thread (128 cols)
  {
    const int lc = tid;                                // 0..127
    const int gcol = (lc >> 5) * Hh + j0 + (lc & 31);  // global gate column
    #pragma unroll 4
    for (int k = 0; k < Hh; ++k) {
      int gi = k * G4 + gcol;
      float w = whh_mu[gi] + softplus_f(whh_rho[gi]) * whh_eps[gi];
      w_hh_lds[lc * WHH_S + k] = f2bf(w);
    }
    #pragma unroll 4
    for (int k = 0; k < Dd; ++k) {
      int gi = k * G4 + gcol;
      float w = wih_mu[gi] + softplus_f(wih_rho[gi]) * wih_eps[gi];
      w_ih_lds[lc * WIH_S + k] = f2bf(w);
    }
  }

  // ---- geometry: wave wv owns hidden-half wv -> tiles rt = gate*2 + wv
  const int lane = tid & 63;
  const int wv   = tid >> 6;
  const int ln   = lane & 15;
  const int q    = lane >> 4;
  const int ko   = q * 8;

  const u16* WhP[4]; const u16* WxP[4];
  #pragma unroll
  for (int gt = 0; gt < 4; ++gt) {
    int rt = gt * 2 + wv;
    WhP[gt] = w_hh_lds + (rt * 16 + ln) * WHH_S + ko;
    WxP[gt] = w_ih_lds + (rt * 16 + ln) * WIH_S + ko;
  }

  const int bat = b0 + ln;   // this lane's batch row (B-operand col)

  // ---- per-lane biases: hidden jj = wv*16 + q*4 + r (4 units, all gates)
  float bs[4][4];
  #pragma unroll
  for (int gt = 0; gt < 4; ++gt)
    #pragma unroll
    for (int r = 0; r < 4; ++r) {
      int colg = gt * Hh + j0 + wv * 16 + q * 4 + r;
      bs[gt][r] = b_mu[colg] + softplus_f(b_rho[colg]) * b_eps[colg];
    }

  // ---- group XCD-uniformity handshake (one-time, system scope).
  int fast;
  {
    const unsigned* xp = xcd_arr + (lane & 15) * 16 + jrow;
    for (;;) {
      unsigned v;
      asm volatile("global_load_dword %0, %1, off sc0 sc1"
                   : "=v"(v) : "v"(xp));
      asm volatile("s_waitcnt vmcnt(0)");
      asm volatile("" : "+v"(v));
      if (__all((int)(v != SENT))) {
        fast = __all((int)(v == mv));
        break;
      }
    }
  }

  __syncthreads();   // weights-in-LDS ready (one-time; only barrier used)

  if (fast)
    run_steps<true >(WhP, WxP, bs, x_bf, h_buf, bat, j0, wv, q, ko);
  else
    run_steps<false>(WhP, WxP, bs, x_bf, h_buf, bat, j0, wv, q, ko);
}

// ---------------------------------------------------------------- epilogue:
// out[b] = h_last[b,:] . lin_w + lin_b
// h(512) lives in slot (511+1)&3 = 0 -> h_buf base (both paths).
// Dispatch-boundary release writes back the per-XCD L2s (R12-verified),
// so fast-path h (dirty L2 lines) is visible here.
__global__ void k_out(const u16* __restrict__ h, const float* __restrict__ lw,
                      const float* __restrict__ lb, float* __restrict__ out)
{
  int b = blockIdx.x * 64 + threadIdx.x;
  if (b >= Bb) return;
  const u16* hr = h + b * Hh;
  float acc = 0.f;
  #pragma unroll 8
  for (int k = 0; k < Hh; ++k) acc += bf2f(hr[k]) * lw[k];
  out[b] = acc + lb[0];
}

extern "C" void kernel_launch(void* const* d_in, const int* in_sizes, int n_in,
                              void* d_out, int out_size, void* d_ws, size_t ws_size,
                              hipStream_t stream)
{
  (void)in_sizes; (void)n_in; (void)out_size; (void)ws_size;
  const float* x       = (const float*)d_in[0];
  const float* wih_mu  = (const float*)d_in[1];
  const float* wih_rho = (const float*)d_in[2];
  const float* wih_eps = (const float*)d_in[3];
  const float* whh_mu  = (const float*)d_in[4];
  const float* whh_rho = (const float*)d_in[5];
  const float* whh_eps = (const float*)d_in[6];
  const float* b_mu    = (const float*)d_in[7];
  const float* b_rho   = (const float*)d_in[8];
  const float* b_eps   = (const float*)d_in[9];
  const float* lin_w   = (const float*)d_in[10];
  const float* lin_b   = (const float*)d_in[11];
  float* out = (float*)d_out;

  // workspace layout
  u16* x_bf  = (u16*)d_ws;                       // T*B*D bf16  = 16 MB
  u16* h_buf = x_bf + (size_t)Tt * Bb * Dd;      // 4 ring slots (1 MB)
                                                 // + 256 u32 xcd table

  k_prep<<<2048, 256, 0, stream>>>(x, x_bf, h_buf);

  hipFuncSetAttribute(reinterpret_cast<const void*>(lstm_main),
                      hipFuncAttributeMaxDynamicSharedMemorySize, SMEM_BYTES);
  lstm_main<<<NGROUP * NCHUNK, 128, SMEM_BYTES, stream>>>(
      whh_mu, whh_rho, whh_eps, wih_mu, wih_rho, wih_eps,
      b_mu, b_rho, b_eps, x_bf, h_buf);

  k_out<<<(Bb + 63) / 64, 64, 0, stream>>>(h_buf, lin_w, lin_b, out);
}